// Round 1
// baseline (1419.610 us; speedup 1.0000x reference)
//
#include <hip/hip_runtime.h>

#define N_NODES 100000
#define N_EDGES 1600000
#define F 64

// ---------------------------------------------------------------------------
// Kernel 1: hn[r][c] = (sum_k h[r][k] * W[k][c]) * norm[r]
// W staged in LDS once per block; grid-stride over row groups of 4.
// ---------------------------------------------------------------------------
__global__ void gemm_norm_kernel(const float* __restrict__ h,
                                 const float* __restrict__ w,
                                 const float* __restrict__ norm,
                                 float* __restrict__ hn) {
    __shared__ float w_lds[F][F];   // 16 KB
    __shared__ float h_lds[4][F];   // 1 KB

    for (int i = threadIdx.x; i < F * F; i += blockDim.x)
        w_lds[i / F][i % F] = w[i];
    __syncthreads();

    const int rl = threadIdx.x >> 6;   // 0..3 (row within group)
    const int c  = threadIdx.x & 63;   // output column

    for (int r0 = blockIdx.x * 4; r0 < N_NODES; r0 += gridDim.x * 4) {
        const int r = r0 + rl;
        h_lds[rl][c] = (r < N_NODES) ? h[(size_t)r * F + c] : 0.f;
        __syncthreads();
        if (r < N_NODES) {
            float acc = 0.f;
#pragma unroll
            for (int k = 0; k < F; ++k)
                acc += h_lds[rl][k] * w_lds[k][c];
            hn[(size_t)r * F + c] = acc * norm[r];
        }
        __syncthreads();
    }
}

// ---------------------------------------------------------------------------
// Kernel 2: for each edge e: out[dst[e]][:] += hn[src[e]][:]
// 16 threads per edge, each handling a float4 slice of the 64-wide row.
// ---------------------------------------------------------------------------
__global__ void scatter_kernel(const float* __restrict__ hn,
                               const int* __restrict__ src,
                               const int* __restrict__ dst,
                               float* __restrict__ out) {
    const long long gid = (long long)blockIdx.x * blockDim.x + threadIdx.x;
    int e = (int)(gid >> 4);
    const int j = (int)(gid & 15);
    const int stride_e = (int)(((long long)gridDim.x * blockDim.x) >> 4);

    for (; e < N_EDGES; e += stride_e) {
        const int s = src[e];
        const int d = dst[e];
        const float4 v = *reinterpret_cast<const float4*>(hn + (size_t)s * F + j * 4);
        float* o = out + (size_t)d * F + j * 4;
        atomicAdd(o + 0, v.x);
        atomicAdd(o + 1, v.y);
        atomicAdd(o + 2, v.z);
        atomicAdd(o + 3, v.w);
    }
}

// ---------------------------------------------------------------------------
// Kernel 3: out[r][c] *= norm[r]   (in place, float4 per thread)
// ---------------------------------------------------------------------------
__global__ void scale_kernel(float* __restrict__ out,
                             const float* __restrict__ norm) {
    const int total = N_NODES * F / 4;
    for (int i = blockIdx.x * blockDim.x + threadIdx.x; i < total;
         i += gridDim.x * blockDim.x) {
        const int row = i >> 4;   // 16 float4 per row
        const float nv = norm[row];
        float4 v = reinterpret_cast<float4*>(out)[i];
        v.x *= nv; v.y *= nv; v.z *= nv; v.w *= nv;
        reinterpret_cast<float4*>(out)[i] = v;
    }
}

extern "C" void kernel_launch(void* const* d_in, const int* in_sizes, int n_in,
                              void* d_out, int out_size, void* d_ws, size_t ws_size,
                              hipStream_t stream) {
    const float* h    = (const float*)d_in[0];
    const float* w    = (const float*)d_in[1];
    const float* norm = (const float*)d_in[2];
    const int*   src  = (const int*)d_in[3];
    const int*   dst  = (const int*)d_in[4];
    float* out = (float*)d_out;
    float* hn  = (float*)d_ws;   // 100000*64 floats = 25.6 MB scratch

    // Zero accumulation target (d_out is poisoned / holds stale results).
    hipMemsetAsync(out, 0, (size_t)N_NODES * F * sizeof(float), stream);

    gemm_norm_kernel<<<2048, 256, 0, stream>>>(h, w, norm, hn);
    scatter_kernel<<<4096, 256, 0, stream>>>(hn, src, dst, out);
    scale_kernel<<<2048, 256, 0, stream>>>(out, norm);
}

// Round 2
// 309.174 us; speedup vs baseline: 4.5916x; 4.5916x over previous
//
#include <hip/hip_runtime.h>

#define N_NODES 100000
#define N_EDGES 1600000
#define F 64
#define SCAN_TILE 1024
#define NB_SCAN ((N_NODES + SCAN_TILE - 1) / SCAN_TILE)   // 98

// ---------------------------------------------------------------------------
// Kernel 1: hn[r][c] = (sum_k h[r][k] * W[k][c]) * norm[r]
// ---------------------------------------------------------------------------
__global__ void gemm_norm_kernel(const float* __restrict__ h,
                                 const float* __restrict__ w,
                                 const float* __restrict__ norm,
                                 float* __restrict__ hn) {
    __shared__ float w_lds[F][F];
    __shared__ float h_lds[4][F];

    for (int i = threadIdx.x; i < F * F; i += blockDim.x)
        w_lds[i / F][i % F] = w[i];
    __syncthreads();

    const int rl = threadIdx.x >> 6;
    const int c  = threadIdx.x & 63;

    for (int r0 = blockIdx.x * 4; r0 < N_NODES; r0 += gridDim.x * 4) {
        const int r = r0 + rl;
        h_lds[rl][c] = (r < N_NODES) ? h[(size_t)r * F + c] : 0.f;
        __syncthreads();
        if (r < N_NODES) {
            float acc = 0.f;
#pragma unroll
            for (int k = 0; k < F; ++k)
                acc += h_lds[rl][k] * w_lds[k][c];
            hn[(size_t)r * F + c] = acc * norm[r];
        }
        __syncthreads();
    }
}

// ---------------------------------------------------------------------------
// CSR build: count -> scan -> place
// ---------------------------------------------------------------------------
__global__ void count_kernel(const int* __restrict__ dst, int* __restrict__ cnt) {
    const int i = blockIdx.x * blockDim.x + threadIdx.x;
    if (i < N_EDGES) atomicAdd(&cnt[dst[i]], 1);
}

// Per-tile exclusive scan (tile = 1024 elems, 256 threads x 4).
__global__ void scan_tile_kernel(const int* __restrict__ cnt,
                                 int* __restrict__ tile_excl,
                                 int* __restrict__ blocksum) {
    __shared__ int lds[256];
    const int t = threadIdx.x;
    const int base = blockIdx.x * SCAN_TILE + t * 4;

    int v[4];
#pragma unroll
    for (int j = 0; j < 4; ++j)
        v[j] = (base + j < N_NODES) ? cnt[base + j] : 0;
    const int s = v[0] + v[1] + v[2] + v[3];

    lds[t] = s;
    __syncthreads();
    int acc = s;
#pragma unroll
    for (int off = 1; off < 256; off <<= 1) {
        int add = (t >= off) ? lds[t - off] : 0;
        __syncthreads();
        acc += add;
        lds[t] = acc;
        __syncthreads();
    }
    int run = acc - s;   // exclusive prefix of this thread's 4-group
#pragma unroll
    for (int j = 0; j < 4; ++j) {
        if (base + j < N_NODES) tile_excl[base + j] = run;
        run += v[j];
    }
    if (t == 255) blocksum[blockIdx.x] = acc;
}

// Add cross-tile base; produce final offsets and a cursor copy.
__global__ void scan_fix_kernel(int* __restrict__ offsets,
                                int* __restrict__ cursor,
                                const int* __restrict__ blocksum) {
    __shared__ int red[256];
    const int t = threadIdx.x;
    const int b = blockIdx.x;

    int partial = 0;
    for (int i = t; i < b; i += 256) partial += blocksum[i];
    red[t] = partial;
    __syncthreads();
#pragma unroll
    for (int off = 128; off > 0; off >>= 1) {
        if (t < off) red[t] += red[t + off];
        __syncthreads();
    }
    const int tile_base = red[0];

    const int base = b * SCAN_TILE + t * 4;
#pragma unroll
    for (int j = 0; j < 4; ++j) {
        const int idx = base + j;
        if (idx < N_NODES) {
            const int o = offsets[idx] + tile_base;
            offsets[idx] = o;
            cursor[idx]  = o;
        }
    }
    if (b == 0 && t == 0) offsets[N_NODES] = N_EDGES;
}

__global__ void place_kernel(const int* __restrict__ src,
                             const int* __restrict__ dst,
                             int* __restrict__ cursor,
                             int* __restrict__ esrc) {
    const int i = blockIdx.x * blockDim.x + threadIdx.x;
    if (i < N_EDGES) {
        const int p = atomicAdd(&cursor[dst[i]], 1);
        esrc[p] = src[i];
    }
}

// ---------------------------------------------------------------------------
// Gather-sum: one wave per dst node, lane = column. Fused post-scale.
// ---------------------------------------------------------------------------
__global__ void gather_kernel(const float* __restrict__ hn,
                              const int* __restrict__ offsets,
                              const int* __restrict__ esrc,
                              const float* __restrict__ norm,
                              float* __restrict__ out) {
    const int node = blockIdx.x * (blockDim.x >> 6) + (threadIdx.x >> 6);
    const int lane = threadIdx.x & 63;
    if (node >= N_NODES) return;

    const int beg = offsets[node];
    const int end = offsets[node + 1];

    float acc = 0.f;
    int i = beg;
    for (; i + 3 < end; i += 4) {
        const int s0 = esrc[i], s1 = esrc[i + 1], s2 = esrc[i + 2], s3 = esrc[i + 3];
        acc += hn[(size_t)s0 * F + lane];
        acc += hn[(size_t)s1 * F + lane];
        acc += hn[(size_t)s2 * F + lane];
        acc += hn[(size_t)s3 * F + lane];
    }
    for (; i < end; ++i)
        acc += hn[(size_t)esrc[i] * F + lane];

    out[(size_t)node * F + lane] = acc * norm[node];
}

extern "C" void kernel_launch(void* const* d_in, const int* in_sizes, int n_in,
                              void* d_out, int out_size, void* d_ws, size_t ws_size,
                              hipStream_t stream) {
    const float* h    = (const float*)d_in[0];
    const float* w    = (const float*)d_in[1];
    const float* norm = (const float*)d_in[2];
    const int*   src  = (const int*)d_in[3];
    const int*   dst  = (const int*)d_in[4];
    float* out = (float*)d_out;

    // Workspace layout (bytes, 256-aligned chunks):
    char* ws = (char*)d_ws;
    float* hn      = (float*)ws;                         // 25,600,000 B
    int*   offsets = (int*)(ws + 25600000);              // 400,128 B ((N+1)*4 rounded)
    int*   cursor  = (int*)(ws + 25600000 + 400128);     // 400,128 B
    int*   blksum  = (int*)(ws + 25600000 + 800256);     // 512 B
    int*   esrc    = (int*)(ws + 25600000 + 800768);     // 6,400,000 B
    // total ~33.2 MB

    // counts accumulate in `cursor` first; zero it.
    hipMemsetAsync(cursor, 0, N_NODES * sizeof(int), stream);

    gemm_norm_kernel<<<2048, 256, 0, stream>>>(h, w, norm, hn);

    count_kernel<<<N_EDGES / 256, 256, 0, stream>>>(dst, cursor);
    scan_tile_kernel<<<NB_SCAN, 256, 0, stream>>>(cursor, offsets, blksum);
    scan_fix_kernel<<<NB_SCAN, 256, 0, stream>>>(offsets, cursor, blksum);
    place_kernel<<<N_EDGES / 256, 256, 0, stream>>>(src, dst, cursor, esrc);

    gather_kernel<<<N_NODES / 4, 256, 0, stream>>>(hn, offsets, esrc, norm, out);
}

// Round 3
// 258.033 us; speedup vs baseline: 5.5017x; 1.1982x over previous
//
#include <hip/hip_runtime.h>

#define N_NODES 100000
#define N_EDGES 1600000
#define F 64
#define SCAN_TILE 1024
#define NB_SCAN ((N_NODES + SCAN_TILE - 1) / SCAN_TILE)   // 98
#define NPASS 8
#define PRANGE (N_NODES / NPASS)   // 12500 exactly

typedef unsigned short ushort_t;
typedef unsigned int uint_t;

// round-to-nearest-even float -> bf16 bits
__device__ __forceinline__ ushort_t f2bf(float x) {
    uint_t u = __float_as_uint(x);
    u += 0x7FFFu + ((u >> 16) & 1u);
    return (ushort_t)(u >> 16);
}
// bf16 bits -> float (exact)
__device__ __forceinline__ float bf2f(ushort_t b) {
    return __uint_as_float(((uint_t)b) << 16);
}

// ---------------------------------------------------------------------------
// Kernel 1: hn[r][c] = bf16( (sum_k h[r][k] * W[k][c]) * norm[r] )
// ---------------------------------------------------------------------------
__global__ void gemm_norm_kernel(const float* __restrict__ h,
                                 const float* __restrict__ w,
                                 const float* __restrict__ norm,
                                 ushort_t* __restrict__ hn) {
    __shared__ float w_lds[F][F];
    __shared__ float h_lds[4][F];

    for (int i = threadIdx.x; i < F * F; i += blockDim.x)
        w_lds[i / F][i % F] = w[i];
    __syncthreads();

    const int rl = threadIdx.x >> 6;
    const int c  = threadIdx.x & 63;

    for (int r0 = blockIdx.x * 4; r0 < N_NODES; r0 += gridDim.x * 4) {
        const int r = r0 + rl;
        h_lds[rl][c] = (r < N_NODES) ? h[(size_t)r * F + c] : 0.f;
        __syncthreads();
        if (r < N_NODES) {
            float acc = 0.f;
#pragma unroll
            for (int k = 0; k < F; ++k)
                acc += h_lds[rl][k] * w_lds[k][c];
            hn[(size_t)r * F + c] = f2bf(acc * norm[r]);
        }
        __syncthreads();
    }
}

// ---------------------------------------------------------------------------
// CSR build: count -> scan -> place
// ---------------------------------------------------------------------------
__global__ void count_kernel(const int* __restrict__ dst, int* __restrict__ cnt) {
    const int i = blockIdx.x * blockDim.x + threadIdx.x;
    if (i < N_EDGES) atomicAdd(&cnt[dst[i]], 1);
}

__global__ void scan_tile_kernel(const int* __restrict__ cnt,
                                 int* __restrict__ tile_excl,
                                 int* __restrict__ blocksum) {
    __shared__ int lds[256];
    const int t = threadIdx.x;
    const int base = blockIdx.x * SCAN_TILE + t * 4;

    int v[4];
#pragma unroll
    for (int j = 0; j < 4; ++j)
        v[j] = (base + j < N_NODES) ? cnt[base + j] : 0;
    const int s = v[0] + v[1] + v[2] + v[3];

    lds[t] = s;
    __syncthreads();
    int acc = s;
#pragma unroll
    for (int off = 1; off < 256; off <<= 1) {
        int add = (t >= off) ? lds[t - off] : 0;
        __syncthreads();
        acc += add;
        lds[t] = acc;
        __syncthreads();
    }
    int run = acc - s;
#pragma unroll
    for (int j = 0; j < 4; ++j) {
        if (base + j < N_NODES) tile_excl[base + j] = run;
        run += v[j];
    }
    if (t == 255) blocksum[blockIdx.x] = acc;
}

__global__ void scan_fix_kernel(int* __restrict__ offsets,
                                int* __restrict__ cursor,
                                const int* __restrict__ blocksum) {
    __shared__ int red[256];
    const int t = threadIdx.x;
    const int b = blockIdx.x;

    int partial = 0;
    for (int i = t; i < b; i += 256) partial += blocksum[i];
    red[t] = partial;
    __syncthreads();
#pragma unroll
    for (int off = 128; off > 0; off >>= 1) {
        if (t < off) red[t] += red[t + off];
        __syncthreads();
    }
    const int tile_base = red[0];

    const int base = b * SCAN_TILE + t * 4;
#pragma unroll
    for (int j = 0; j < 4; ++j) {
        const int idx = base + j;
        if (idx < N_NODES) {
            const int o = offsets[idx] + tile_base;
            offsets[idx] = o;
            cursor[idx]  = o;
        }
    }
    if (b == 0 && t == 0) offsets[N_NODES] = N_EDGES;
}

// Multi-pass place: pass p handles dst in [p*PRANGE, (p+1)*PRANGE).
// pass = blockIdx.x & 7 rides the round-robin blockIdx->XCD mapping so each
// pass's esrc write window (~800 KB) accumulates full lines in ONE L2.
__global__ void place_kernel(const int* __restrict__ src,
                             const int* __restrict__ dst,
                             int* __restrict__ cursor,
                             int* __restrict__ esrc) {
    const int pass  = blockIdx.x & (NPASS - 1);
    const int chunk = blockIdx.x >> 3;
    const int nchunk = gridDim.x >> 3;
    const int lo = pass * PRANGE;
    const int hi = lo + PRANGE;

    for (int i = chunk * blockDim.x + threadIdx.x; i < N_EDGES;
         i += nchunk * blockDim.x) {
        const int d = dst[i];
        const int s = src[i];
        if (d >= lo && d < hi) {
            const int p = atomicAdd(&cursor[d], 1);
            esrc[p] = s;
        }
    }
}

// ---------------------------------------------------------------------------
// Gather-sum: one wave per dst node, lane = column (bf16 hn). Fused post-scale.
// ---------------------------------------------------------------------------
__global__ void gather_kernel(const ushort_t* __restrict__ hn,
                              const int* __restrict__ offsets,
                              const int* __restrict__ esrc,
                              const float* __restrict__ norm,
                              float* __restrict__ out) {
    const int node = blockIdx.x * (blockDim.x >> 6) + (threadIdx.x >> 6);
    const int lane = threadIdx.x & 63;
    if (node >= N_NODES) return;

    const int beg = offsets[node];
    const int end = offsets[node + 1];

    float acc = 0.f;
    int i = beg;
    for (; i + 3 < end; i += 4) {
        const int s0 = esrc[i], s1 = esrc[i + 1], s2 = esrc[i + 2], s3 = esrc[i + 3];
        const ushort_t a = hn[(size_t)s0 * F + lane];
        const ushort_t b = hn[(size_t)s1 * F + lane];
        const ushort_t c = hn[(size_t)s2 * F + lane];
        const ushort_t d = hn[(size_t)s3 * F + lane];
        acc += bf2f(a) + bf2f(b) + bf2f(c) + bf2f(d);
    }
    for (; i < end; ++i)
        acc += bf2f(hn[(size_t)esrc[i] * F + lane]);

    out[(size_t)node * F + lane] = acc * norm[node];
}

extern "C" void kernel_launch(void* const* d_in, const int* in_sizes, int n_in,
                              void* d_out, int out_size, void* d_ws, size_t ws_size,
                              hipStream_t stream) {
    const float* h    = (const float*)d_in[0];
    const float* w    = (const float*)d_in[1];
    const float* norm = (const float*)d_in[2];
    const int*   src  = (const int*)d_in[3];
    const int*   dst  = (const int*)d_in[4];
    float* out = (float*)d_out;

    // Workspace layout (256-aligned chunks):
    char* ws = (char*)d_ws;
    ushort_t* hn     = (ushort_t*)ws;                       // 12,800,000 B
    int* offsets = (int*)(ws + 12800000);                   // 400,128 B
    int* cursor  = (int*)(ws + 12800000 + 400128);          // 400,128 B
    int* blksum  = (int*)(ws + 12800000 + 800256);          // 512 B
    int* esrc    = (int*)(ws + 12800000 + 800768);          // 6,400,000 B
    // total ~19.2 MB

    hipMemsetAsync(cursor, 0, N_NODES * sizeof(int), stream);

    gemm_norm_kernel<<<2048, 256, 0, stream>>>(h, w, norm, hn);

    count_kernel<<<N_EDGES / 256, 256, 0, stream>>>(dst, cursor);
    scan_tile_kernel<<<NB_SCAN, 256, 0, stream>>>(cursor, offsets, blksum);
    scan_fix_kernel<<<NB_SCAN, 256, 0, stream>>>(offsets, cursor, blksum);
    place_kernel<<<16384, 256, 0, stream>>>(src, dst, cursor, esrc);

    gather_kernel<<<N_NODES / 4, 256, 0, stream>>>(hn, offsets, esrc, norm, out);
}